// Round 7
// baseline (124.464 us; speedup 1.0000x reference)
//
#include <hip/hip_runtime.h>

// YOLO-v1 style loss on MI355X (gfx950).
// Inputs: d_in[0] = output (BATCH*S*S*30 fp32), d_in[1] = target (same).
// Outputs: d_out[0..2] = (loss, sum_iou, acc) as fp32.
//
// History:
//  R1/R2 (~175-220us): 1568 blocks x 8 atomicAdds to ONE cache line.
//  R3/R4/R6 (kernel ~40us, invariant): atomics fixed; load-balance (R4) and
//    barrier removal (R6) both NEUTRAL. Common factor: 61952B LDS -> 2
//    blocks/CU -> 16.7% occupancy -> latency-bound at 2 waves/SIMD.
//  R5 FAILED: global_load_lds width=12 unverified -> NaN. 16B-only is safe.
//  R7: ONE per-wave LDS slice (7680B) reused A-then-B; A+B global loads
//    issued together into VGPRs (single latency exposure); LDS/block
//    30720B -> 5 blocks/CU -> 20 waves/CU. Ballot-based integer counts.

#define NACC 8
#define WAVES_PER_BLOCK 4
#define WAVE_CELLS 64
#define SLICE_FLOATS (WAVE_CELLS * 30)   // 1920 floats = 7680 B
#define SLICE_F4     (SLICE_FLOATS / 4)  // 480 float4

__device__ __forceinline__ float wave_reduce_sum(float v) {
    #pragma unroll
    for (int off = 32; off > 0; off >>= 1)
        v += __shfl_down(v, off, 64);
    return v;
}

__global__ __launch_bounds__(256) void yolo_loss_kernel(
        const float* __restrict__ out,
        const float* __restrict__ tgt,
        float* __restrict__ partials, int N) {
    // ONE private slice per wave; no cross-wave sharing -> no barriers.
    __shared__ float s[WAVES_PER_BLOCK][SLICE_FLOATS];   // 30720 B total

    const int wid  = threadIdx.x >> 6;
    const int lane = threadIdx.x & 63;
    const int row  = blockIdx.x * WAVES_PER_BLOCK + wid;
    const int cell0 = row * WAVE_CELLS;

    float* ls = s[wid];
    float4* ls4 = (float4*)ls;

    float v[NACC];
    #pragma unroll
    for (int k = 0; k < NACC; k++) v[k] = 0.f;

    const int cells = min(WAVE_CELLS, N - cell0);
    const bool active = (lane < cells);

    float ov[30], tv[30];
    bool is_obj = false, is_correct = false;

    if (cells == WAVE_CELLS) {
        const float4* gA = (const float4*)(out + (size_t)cell0 * 30);
        const float4* gB = (const float4*)(tgt + (size_t)cell0 * 30);
        // Issue ALL global loads up front: one latency exposure for A and B.
        float4 aR[8], bR[8];
        #pragma unroll
        for (int j = 0; j < 8; j++) {
            const int f = j * 64 + lane;
            if (f < SLICE_F4) aR[j] = gA[f];
        }
        #pragma unroll
        for (int j = 0; j < 8; j++) {
            const int f = j * 64 + lane;
            if (f < SLICE_F4) bR[j] = gB[f];
        }
        // Stage A, read own row (same-wave DS ops are in-order; no barrier).
        #pragma unroll
        for (int j = 0; j < 8; j++) {
            const int f = j * 64 + lane;
            if (f < SLICE_F4) ls4[f] = aR[j];
        }
        {
            const float2* a2 = (const float2*)(ls + lane * 30);
            #pragma unroll
            for (int k = 0; k < 15; k++) {
                const float2 x = a2[k];
                ov[2 * k] = x.x; ov[2 * k + 1] = x.y;
            }
        }
        // Reuse slice for B (WAR vs A-reads kept by per-wave DS ordering).
        #pragma unroll
        for (int j = 0; j < 8; j++) {
            const int f = j * 64 + lane;
            if (f < SLICE_F4) ls4[f] = bR[j];
        }
        {
            const float2* b2 = (const float2*)(ls + lane * 30);
            #pragma unroll
            for (int k = 0; k < 15; k++) {
                const float2 x = b2[k];
                tv[2 * k] = x.x; tv[2 * k + 1] = x.y;
            }
        }
    } else if (cells > 0) {
        // tail fallback (never taken for N=401408): sequential A then B
        for (int f = lane; f < cells * 30; f += 64)
            ls[f] = out[(size_t)cell0 * 30 + f];
        if (active) {
            #pragma unroll
            for (int k = 0; k < 30; k++) ov[k] = ls[lane * 30 + k];
        }
        for (int f = lane; f < cells * 30; f += 64)
            ls[f] = tgt[(size_t)cell0 * 30 + f];
        if (active) {
            #pragma unroll
            for (int k = 0; k < 30; k++) tv[k] = ls[lane * 30 + k];
        }
    }

    if (active) {
        const float m = (tv[4] > 0.f) ? 1.f : 0.f;

        // target corners (xy/S +- 0.5*wh), matching reference arithmetic
        const float tx0 = tv[0] / 7.f - 0.5f * tv[2];
        const float ty0 = tv[1] / 7.f - 0.5f * tv[3];
        const float tx1 = tv[0] / 7.f + 0.5f * tv[2];
        const float ty1 = tv[1] / 7.f + 0.5f * tv[3];
        const float at  = (tx1 - tx0) * (ty1 - ty0);

        float iou[2];
        #pragma unroll
        for (int b = 0; b < 2; b++) {
            const float* pb = ov + b * 5;
            const float px0 = pb[0] / 7.f - 0.5f * pb[2];
            const float py0 = pb[1] / 7.f - 0.5f * pb[3];
            const float px1 = pb[0] / 7.f + 0.5f * pb[2];
            const float py1 = pb[1] / 7.f + 0.5f * pb[3];
            const float ap  = (px1 - px0) * (py1 - py0);
            const float ulx = fmaxf(px0, tx0), uly = fmaxf(py0, ty0);
            const float lrx = fminf(px1, tx1), lry = fminf(py1, ty1);
            const float wi  = fmaxf(lrx - ulx, 0.f);
            const float hi  = fmaxf(lry - uly, 0.f);
            const float inter = wi * hi;
            iou[b] = inter / (ap + at - inter);
        }

        // argmax, first-max tie-break: resp=1 only if strictly greater
        const int resp = (iou[1] > iou[0]) ? 1 : 0;
        const float max_iou = fmaxf(iou[0], iou[1]);
        const float min_iou = fminf(iou[0], iou[1]);
        const float* rb = ov + resp * 5;
        const float* nb = ov + (1 - resp) * 5;

        {
            const float dx = rb[0] - tv[0];
            const float dy = rb[1] - tv[1];
            const float dw = sqrtf(rb[2]) - sqrtf(tv[2]);
            const float dh = sqrtf(rb[3]) - sqrtf(tv[3]);
            v[1] = m * (dx * dx + dy * dy + dw * dw + dh * dh);
        }
        {
            const float d = rb[4] - max_iou;
            v[2] = m * d * d;
        }
        v[3] = m * nb[4] * nb[4];
        {
            const float d0 = ov[4] - tv[4];
            const float d1 = ov[9] - tv[9];
            v[4] = (1.f - m) * (d0 * d0 + d1 * d1);
        }

        // class loss + argmax accuracy (first-max semantics via strict >)
        float cls_sum = 0.f;
        int oarg = 0, targ = 0;
        float obest = ov[10], tbest = tv[10];
        #pragma unroll
        for (int c = 0; c < 20; c++) {
            const float oc = ov[10 + c], tc = tv[10 + c];
            const float d = oc - tc;
            cls_sum += d * d;
            if (oc > obest) { obest = oc; oarg = c; }
            if (tc > tbest) { tbest = tc; targ = c; }
        }
        v[5] = m * cls_sum;
        v[6] = m * min_iou;
        is_obj = (m > 0.f);
        is_correct = is_obj && (oarg == targ);
    }

    // Counts via ballot (exact integers, no shuffle chains needed).
    const float n_obj_w = (float)__popcll(__ballot(is_obj));
    const float acc_w   = (float)__popcll(__ballot(is_correct));

    // 6 float sums via wave shuffle reduce; per-wave partial store.
    #pragma unroll
    for (int k = 1; k <= 6; k++) v[k] = wave_reduce_sum(v[k]);
    if (lane == 0) {
        float* p = partials + (size_t)row * NACC;
        p[0] = n_obj_w;
        #pragma unroll
        for (int k = 1; k <= 6; k++) p[k] = v[k];
        p[7] = acc_w;
    }
}

__global__ __launch_bounds__(256) void yolo_finalize_kernel(
        const float* __restrict__ partials,
        float* __restrict__ res, int N, int nRows) {
    __shared__ float sred[4][NACC];
    float v[NACC];
    #pragma unroll
    for (int k = 0; k < NACC; k++) v[k] = 0.f;
    // rows are 8 floats = 2 float4
    const float4* p4 = (const float4*)partials;
    for (int b = threadIdx.x; b < nRows; b += 256) {
        const float4 x = p4[b * 2 + 0];
        const float4 y = p4[b * 2 + 1];
        v[0] += x.x; v[1] += x.y; v[2] += x.z; v[3] += x.w;
        v[4] += y.x; v[5] += y.y; v[6] += y.z; v[7] += y.w;
    }
    const int lane = threadIdx.x & 63;
    const int wid  = threadIdx.x >> 6;
    #pragma unroll
    for (int k = 0; k < NACC; k++) v[k] = wave_reduce_sum(v[k]);
    if (lane == 0) {
        #pragma unroll
        for (int k = 0; k < NACC; k++) sred[wid][k] = v[k];
    }
    __syncthreads();
    if (threadIdx.x == 0) {
        float acc[NACC];
        #pragma unroll
        for (int k = 0; k < NACC; k++)
            acc[k] = sred[0][k] + sred[1][k] + sred[2][k] + sred[3][k];
        const float n_obj   = acc[0];
        const float n_noobj = (float)N - n_obj;
        const float contain     = acc[1] / (2.f * n_obj);
        const float obj_loss    = acc[2] / n_obj;
        const float not_contain = acc[3] / n_obj;
        const float noobj_loss  = acc[4] / (2.f * n_noobj);
        const float class_loss  = acc[5] / (n_obj * 20.f);
        res[0] = 5.f * contain + obj_loss
               + 0.5f * (noobj_loss + not_contain) + class_loss;
        res[1] = acc[6];
        res[2] = acc[7];
    }
}

extern "C" void kernel_launch(void* const* d_in, const int* in_sizes, int n_in,
                              void* d_out, int out_size, void* d_ws, size_t ws_size,
                              hipStream_t stream) {
    const float* out_p = (const float*)d_in[0];
    const float* tgt_p = (const float*)d_in[1];
    float* ws  = (float*)d_ws;   // nRows * 8 partial sums
    float* res = (float*)d_out;
    const int N = in_sizes[0] / 30;                          // 401408 cells
    const int cellsPerBlock = WAVES_PER_BLOCK * WAVE_CELLS;  // 256
    const int nBlocks = (N + cellsPerBlock - 1) / cellsPerBlock;  // 1568
    const int nRows = nBlocks * WAVES_PER_BLOCK;             // 6272

    yolo_loss_kernel<<<nBlocks, 256, 0, stream>>>(out_p, tgt_p, ws, N);
    yolo_finalize_kernel<<<1, 256, 0, stream>>>(ws, res, N, nRows);
}